// Round 1
// baseline (310.551 us; speedup 1.0000x reference)
//
#include <hip/hip_runtime.h>

typedef float  floatx4  __attribute__((ext_vector_type(4)));
typedef short  bf16x8   __attribute__((ext_vector_type(8)));
typedef float  facc4    __attribute__((ext_vector_type(4)));

__device__ __forceinline__ unsigned short f2bf(float f) {
  unsigned u = __builtin_bit_cast(unsigned, f);
  u = u + 0x7fffu + ((u >> 16) & 1u);   // round-to-nearest-even
  return (unsigned short)(u >> 16);
}

// ---------------- K1: cos/sin tables ----------------
__global__ void k_sincos(const float* __restrict__ ang, float* __restrict__ cs) {
  int i = blockIdx.x * 256 + threadIdx.x;
  if (i < 8128) {
    float s, c;
    sincosf(ang[i], &s, &c);
    cs[2 * i]     = c;
    cs[2 * i + 1] = s;
  }
}

// ---------------- K2: chunk partial products ----------------
// Thread r holds row r of the chunk product in 128 VGPRs (compile-time indices).
// Rotation (i,j): wi' = wi*c + wj*s ; wj' = wj*c - wi*s  (col ops -> row-independent)
template <int I0, int I1>
__device__ void gen_chunk(const float* __restrict__ cs, float* __restrict__ out, int row) {
  float w[128];
#pragma unroll
  for (int k = 0; k < 128; ++k) w[k] = (k == row) ? 1.0f : 0.0f;
#pragma unroll
  for (int i = I0; i < I1; ++i) {
    float wi = w[i];
#pragma unroll
    for (int j = i + 1; j < 128; ++j) {
      const int p = i * 127 - (i * (i - 1)) / 2 + (j - i - 1);  // lex pair index
      const float c = cs[2 * p];
      const float s = cs[2 * p + 1];
      const float wj = w[j];
      const float nwi = fmaf(wj, s, wi * c);
      w[j] = fmaf(wj, c, -(wi * s));
      wi = nwi;
    }
    w[i] = wi;
  }
  floatx4* o = (floatx4*)(out + row * 128);
#pragma unroll
  for (int k = 0; k < 32; ++k) {
    floatx4 v;
    v[0] = w[4 * k]; v[1] = w[4 * k + 1]; v[2] = w[4 * k + 2]; v[3] = w[4 * k + 3];
    o[k] = v;
  }
}

__global__ __launch_bounds__(128) void k_chunks(const float* __restrict__ cs,
                                                float* __restrict__ out) {
  const int row = threadIdx.x;
  // i-boundaries balancing ~1016 rotations/chunk: {0,8,17,27,37,49,64,82,127}
  switch (blockIdx.x) {
    case 0:  gen_chunk<0,   8>(cs, out + 0 * 16384, row); break;
    case 1:  gen_chunk<8,  17>(cs, out + 1 * 16384, row); break;
    case 2:  gen_chunk<17, 27>(cs, out + 2 * 16384, row); break;
    case 3:  gen_chunk<27, 37>(cs, out + 3 * 16384, row); break;
    case 4:  gen_chunk<37, 49>(cs, out + 4 * 16384, row); break;
    case 5:  gen_chunk<49, 64>(cs, out + 5 * 16384, row); break;
    case 6:  gen_chunk<64, 82>(cs, out + 6 * 16384, row); break;
    default: gen_chunk<82, 127>(cs, out + 7 * 16384, row); break;
  }
}

// ---------------- K3: combine W = C0*C1*...*C7, emit Wt bf16 [n][136] ----------------
__global__ __launch_bounds__(128) void k_combine(const float* __restrict__ chunks,
                                                 unsigned short* __restrict__ wt) {
  __shared__ float sv[128];
  const int r = blockIdx.x;   // row of W (k index of GEMM B)
  const int t = threadIdx.x;  // column of W (n index)
  float v = chunks[r * 128 + t];  // row r of C0
#pragma unroll
  for (int m = 1; m < 8; ++m) {
    __syncthreads();
    sv[t] = v;
    __syncthreads();
    const float* Cm = chunks + m * 16384;
    float acc = 0.0f;
#pragma unroll
    for (int k = 0; k < 128; ++k) acc = fmaf(sv[k], Cm[k * 128 + t], acc);
    v = acc;
  }
  wt[t * 136 + r] = f2bf(v);  // Wt[n][k], leading dim 136 (16B-aligned, bank-balanced)
}

// ---------------- K4: y = x @ W + bias  (bf16 MFMA, fp32 acc) ----------------
__global__ __launch_bounds__(256) void k_gemm(const float* __restrict__ x,
                                              const unsigned short* __restrict__ wt,
                                              const float* __restrict__ bias,
                                              float* __restrict__ y) {
  __shared__ unsigned short sW[128 * 136];  // 34816 B
  __shared__ float sB[128];
  const int tid = threadIdx.x;
  {
    const floatx4* src = (const floatx4*)wt;
    floatx4* dst = (floatx4*)sW;
#pragma unroll
    for (int i2 = 0; i2 < 9; ++i2) {
      int idx = tid + i2 * 256;
      if (idx < 2176) dst[idx] = src[idx];  // 34816/16 = 2176
    }
    if (tid < 128) sB[tid] = bias[tid];
  }
  __syncthreads();

  const int wave = tid >> 6, lane = tid & 63;
  const int m16 = lane & 15, h = lane >> 4;

  for (int it = 0; it < 4; ++it) {
    const int base_row = blockIdx.x * 256 + (wave * 4 + it) * 16;
    const float* xr = x + (size_t)(base_row + m16) * 128;
    // lane reads 32B contiguous per K-chunk: k in [c*32 + h*8, +8)
    floatx4 a[8];
#pragma unroll
    for (int c = 0; c < 4; ++c) {
      a[2 * c]     = *(const floatx4*)(xr + c * 32 + h * 8);
      a[2 * c + 1] = *(const floatx4*)(xr + c * 32 + h * 8 + 4);
    }
    facc4 acc[8];
#pragma unroll
    for (int t = 0; t < 8; ++t) {
#pragma unroll
      for (int rr = 0; rr < 4; ++rr) acc[t][rr] = 0.0f;
    }
#pragma unroll
    for (int c = 0; c < 4; ++c) {
      bf16x8 af;
#pragma unroll
      for (int q = 0; q < 8; ++q) {
        const float f = (q < 4) ? a[2 * c][q] : a[2 * c + 1][q - 4];
        af[q] = (short)f2bf(f);
      }
#pragma unroll
      for (int t = 0; t < 8; ++t) {
        // B[k][n]: lane&15 = n, 8 consecutive k at c*32 + h*8
        const bf16x8 bfr = *(const bf16x8*)(&sW[(t * 16 + m16) * 136 + c * 32 + h * 8]);
        acc[t] = __builtin_amdgcn_mfma_f32_16x16x32_bf16(af, bfr, acc[t], 0, 0, 0);
      }
    }
#pragma unroll
    for (int t = 0; t < 8; ++t) {
      const float b = sB[t * 16 + m16];
#pragma unroll
      for (int rr = 0; rr < 4; ++rr) {
        const int row = base_row + h * 4 + rr;  // D: row=(lane>>4)*4+reg, col=lane&15
        y[(size_t)row * 128 + t * 16 + m16] = acc[t][rr] + b;
      }
    }
  }
}

extern "C" void kernel_launch(void* const* d_in, const int* in_sizes, int n_in,
                              void* d_out, int out_size, void* d_ws, size_t ws_size,
                              hipStream_t stream) {
  const float* x    = (const float*)d_in[0];
  const float* ang  = (const float*)d_in[1];
  const float* bias = (const float*)d_in[2];
  float* y = (float*)d_out;

  char* ws = (char*)d_ws;
  float* cs               = (float*)ws;                       // 65024 B
  float* chunks           = (float*)(ws + 65536);             // 8 * 64 KiB
  unsigned short* wt      = (unsigned short*)(ws + 65536 + 524288);  // 34816 B

  k_sincos <<<32,   256, 0, stream>>>(ang, cs);
  k_chunks <<<8,    128, 0, stream>>>(cs, chunks);
  k_combine<<<128,  128, 0, stream>>>(chunks, wt);
  k_gemm   <<<1024, 256, 0, stream>>>(x, wt, bias, y);
}

// Round 2
// 288.333 us; speedup vs baseline: 1.0771x; 1.0771x over previous
//
#include <hip/hip_runtime.h>

typedef float  floatx4  __attribute__((ext_vector_type(4)));
typedef short  bf16x8   __attribute__((ext_vector_type(8)));
typedef float  facc4    __attribute__((ext_vector_type(4)));

__device__ __forceinline__ unsigned short f2bf(float f) {
  unsigned u = __builtin_bit_cast(unsigned, f);
  u = u + 0x7fffu + ((u >> 16) & 1u);   // round-to-nearest-even
  return (unsigned short)(u >> 16);
}

// ---------------- K1: chunk partial products (sincos fused, cs staged in LDS) ---------
// Thread r<128 holds row r of the chunk product in 128 VGPRs (compile-time indices).
// Rotation (i,j): wi' = wi*c + wj*s ; wj' = wj*c - wi*s  (column ops -> row-independent)
template <int I0, int I1>
__device__ void gen_chunk(const float* __restrict__ ang, float* __restrict__ out,
                          float* lcs, int tid) {
  constexpr int P0 = I0 * 127 - I0 * (I0 - 1) / 2;
  constexpr int P1 = I1 * 127 - I1 * (I1 - 1) / 2;
  constexpr int NROT = P1 - P0;
  // cooperative sincos staging into LDS (256 threads)
  for (int idx = tid; idx < NROT; idx += 256) {
    float s, c;
    sincosf(ang[P0 + idx], &s, &c);
    lcs[2 * idx] = c;
    lcs[2 * idx + 1] = s;
  }
  __syncthreads();
  if (tid >= 128) return;
  float w[128];
#pragma unroll
  for (int k = 0; k < 128; ++k) w[k] = (k == tid) ? 1.0f : 0.0f;
#pragma unroll
  for (int i = I0; i < I1; ++i) {
    float wi = w[i];
#pragma unroll
    for (int j = i + 1; j < 128; ++j) {
      const int p = (i * 127 - (i * (i - 1)) / 2 + (j - i - 1)) - P0;  // compile-time
      const float2 cs2 = *(const float2*)(&lcs[2 * p]);  // ds_read_b64, broadcast
      const float c = cs2.x, s = cs2.y;
      const float wj = w[j];
      w[j] = fmaf(wj, c, -(wi * s));
      wi   = fmaf(wj, s, wi * c);
    }
    w[i] = wi;
  }
  floatx4* o = (floatx4*)(out + (size_t)tid * 128);
#pragma unroll
  for (int k = 0; k < 32; ++k) {
    floatx4 v;
    v[0] = w[4 * k]; v[1] = w[4 * k + 1]; v[2] = w[4 * k + 2]; v[3] = w[4 * k + 3];
    o[k] = v;
  }
}

__global__ __launch_bounds__(256) void k_wgen(const float* __restrict__ ang,
                                              float* __restrict__ out) {
  __shared__ float lcs[2144];  // max chunk = 1065 rotations
  const int tid = threadIdx.x;
  // i-boundaries balancing ~1016 rotations/chunk: {0,8,17,27,37,49,64,82,127}
  switch (blockIdx.x) {
    case 0:  gen_chunk<0,   8>(ang, out + 0 * 16384, lcs, tid); break;
    case 1:  gen_chunk<8,  17>(ang, out + 1 * 16384, lcs, tid); break;
    case 2:  gen_chunk<17, 27>(ang, out + 2 * 16384, lcs, tid); break;
    case 3:  gen_chunk<27, 37>(ang, out + 3 * 16384, lcs, tid); break;
    case 4:  gen_chunk<37, 49>(ang, out + 4 * 16384, lcs, tid); break;
    case 5:  gen_chunk<49, 64>(ang, out + 5 * 16384, lcs, tid); break;
    case 6:  gen_chunk<64, 82>(ang, out + 6 * 16384, lcs, tid); break;
    default: gen_chunk<82, 127>(ang, out + 7 * 16384, lcs, tid); break;
  }
}

// ---------------- K2: combine W = C0*C1*...*C7, emit Wt bf16 [n][136] ----------------
__global__ __launch_bounds__(128) void k_combine(const float* __restrict__ chunks,
                                                 unsigned short* __restrict__ wt) {
  __shared__ float sv[128];
  const int r = blockIdx.x;   // row of W (k index of GEMM B)
  const int t = threadIdx.x;  // column of W (n index)
  float v = chunks[r * 128 + t];  // row r of C0
  for (int m = 1; m < 8; ++m) {
    __syncthreads();
    sv[t] = v;
    __syncthreads();
    const float* Cm = chunks + m * 16384 + t;
    float a0 = 0.f, a1 = 0.f, a2 = 0.f, a3 = 0.f;  // ILP-4: break the FMA chain
#pragma unroll
    for (int k = 0; k < 128; k += 4) {
      a0 = fmaf(sv[k],     Cm[(k)     * 128], a0);
      a1 = fmaf(sv[k + 1], Cm[(k + 1) * 128], a1);
      a2 = fmaf(sv[k + 2], Cm[(k + 2) * 128], a2);
      a3 = fmaf(sv[k + 3], Cm[(k + 3) * 128], a3);
    }
    v = (a0 + a1) + (a2 + a3);
  }
  wt[t * 136 + r] = f2bf(v);  // Wt[n][k], leading dim 136
}

// ---------------- K3: y = x @ W + bias  (bf16 MFMA, fp32 acc) ----------------
// A = Wt (features on M), B = x (batch on N)  ->  lane's 4 acc regs are 4
// consecutive FEATURES for one batch row  ->  dwordx4 stores along the 128-dim.
__global__ __launch_bounds__(256) void k_gemm(const float* __restrict__ x,
                                              const unsigned short* __restrict__ wt,
                                              const float* __restrict__ bias,
                                              float* __restrict__ y) {
  __shared__ unsigned short sW[128 * 136];  // 34816 B
  __shared__ float sB[128];
  const int tid = threadIdx.x;
  {
    const floatx4* src = (const floatx4*)wt;
    floatx4* dst = (floatx4*)sW;
#pragma unroll
    for (int i2 = 0; i2 < 9; ++i2) {
      int idx = tid + i2 * 256;
      if (idx < 2176) dst[idx] = src[idx];
    }
    if (tid < 128) sB[tid] = bias[tid];
  }
  __syncthreads();

  const int wave = tid >> 6, lane = tid & 63;
  const int m16 = lane & 15, h = lane >> 4;

  const size_t row0 = (size_t)blockIdx.x * 256 + wave * 64 + m16;
  const float* xr0 = x + row0 * 128;
  float* yr0 = y + row0 * 128;

  floatx4 a[8];
#pragma unroll
  for (int c = 0; c < 4; ++c) {  // prologue: iteration-0 loads
    a[2 * c]     = *(const floatx4*)(xr0 + c * 32 + h * 8);
    a[2 * c + 1] = *(const floatx4*)(xr0 + c * 32 + h * 8 + 4);
  }

#pragma unroll
  for (int it = 0; it < 4; ++it) {
    // convert current iteration's x to bf16 (frees a[] for the next prefetch)
    bf16x8 af[4];
#pragma unroll
    for (int c = 0; c < 4; ++c) {
#pragma unroll
      for (int q = 0; q < 8; ++q) {
        const float f = (q < 4) ? a[2 * c][q] : a[2 * c + 1][q - 4];
        af[c][q] = (short)f2bf(f);
      }
    }
    // prefetch next iteration's x (2-deep pipeline)
    if (it < 3) {
      const float* xr = xr0 + (size_t)(it + 1) * 16 * 128;
#pragma unroll
      for (int c = 0; c < 4; ++c) {
        a[2 * c]     = *(const floatx4*)(xr + c * 32 + h * 8);
        a[2 * c + 1] = *(const floatx4*)(xr + c * 32 + h * 8 + 4);
      }
    }
    // acc init = bias (C operand of MFMA): reg r holds feature t*16 + h*4 + r
    facc4 acc[8];
#pragma unroll
    for (int t = 0; t < 8; ++t) acc[t] = *(const facc4*)(sB + t * 16 + h * 4);
#pragma unroll
    for (int c = 0; c < 4; ++c) {
#pragma unroll
      for (int t = 0; t < 8; ++t) {
        // A[m=lane&15][k=h*8+j] = Wt[t*16+m16][c*32+h*8+j]
        const bf16x8 bw = *(const bf16x8*)(&sW[(t * 16 + m16) * 136 + c * 32 + h * 8]);
        acc[t] = __builtin_amdgcn_mfma_f32_16x16x32_bf16(bw, af[c], acc[t], 0, 0, 0);
      }
    }
    float* yr = yr0 + (size_t)it * 16 * 128;
#pragma unroll
    for (int t = 0; t < 8; ++t) {
      *(floatx4*)(yr + t * 16 + h * 4) = acc[t];  // 16B contiguous along features
    }
  }
}

extern "C" void kernel_launch(void* const* d_in, const int* in_sizes, int n_in,
                              void* d_out, int out_size, void* d_ws, size_t ws_size,
                              hipStream_t stream) {
  const float* x    = (const float*)d_in[0];
  const float* ang  = (const float*)d_in[1];
  const float* bias = (const float*)d_in[2];
  float* y = (float*)d_out;

  char* ws = (char*)d_ws;
  float* chunks      = (float*)ws;                    // 8 * 64 KiB = 524288 B
  unsigned short* wt = (unsigned short*)(ws + 524288);  // 34816 B

  k_wgen   <<<8,    256, 0, stream>>>(ang, chunks);
  k_combine<<<128,  128, 0, stream>>>(chunks, wt);
  k_gemm   <<<1024, 256, 0, stream>>>(x, wt, bias, y);
}